// Round 1
// 619.119 us; speedup vs baseline: 1.0541x; 1.0541x over previous
//
#include <hip/hip_runtime.h>

// ---------------- constants ----------------
#define NTOK 65536
#define DIN  1024
#define H    512
#define HH   256
#define NREG 16
#define MPR  4096   // patches per region = NTOK/NREG

// ---------------- helpers ----------------
__device__ __forceinline__ unsigned short f2bf(float f) {
  unsigned u = __float_as_uint(f);
  u += 0x7fffu + ((u >> 16) & 1u);   // RNE
  return (unsigned short)(u >> 16);
}
__device__ __forceinline__ float bf2f(unsigned short s) {
  return __uint_as_float(((unsigned)s) << 16);
}
__device__ __forceinline__ float gelu_exact(float x) {
  return 0.5f * x * (1.0f + erff(x * 0.70710678118654752440f));
}
// packed fp32x2 -> bf16x2 (hardware RNE convert, 1 instr) — guide T12 recipe
__device__ __forceinline__ unsigned cvt_pk_bf16(float lo, float hi) {
  unsigned r;
  asm("v_cvt_pk_bf16_f32 %0, %1, %2" : "=v"(r) : "v"(lo), "v"(hi));
  return r;
}
__device__ __forceinline__ unsigned short f2bf_hw(float f) {
  unsigned r;
  asm("v_cvt_pk_bf16_f32 %0, %1, %2" : "=v"(r) : "v"(f), "v"(f));
  return (unsigned short)r;
}
// fast tanh: 1 - 2/(exp(2x)+1); monotone, saturates to ±1, no NaN at |x|→inf
__device__ __forceinline__ float fast_tanh(float x) {
  float e = __expf(2.0f * x);
  return 1.0f - 2.0f * __builtin_amdgcn_rcpf(e + 1.0f);
}

typedef __attribute__((ext_vector_type(8))) short shortx8;       // 8 bf16 (4 VGPRs)
typedef __attribute__((ext_vector_type(4))) float floatx4;       // 4 fp32
typedef __attribute__((ext_vector_type(4))) unsigned int uintx4; // 16B store

__device__ __forceinline__ void gl_lds16(const void* g, void* l) {
  __builtin_amdgcn_global_load_lds(
      (const __attribute__((address_space(1))) void*)g,
      (__attribute__((address_space(3))) void*)l, 16, 0, 0);
}

// chunk-XOR swizzle: 16B chunk for (row, seg) lives at linear slot row*4 + (seg^((row>>1)&3)).
// Spreads the 16 l15-lanes of a ds_read_b128 column-read across all 32 banks (2 lanes/bank = free).
// Involution: applied on the WRITE side (A: ds_write addr; B: permuted global source for
// global_load_lds with linear LDS dest — rule #21) and identically on the READ side.
__device__ __forceinline__ int swz8(int row, int seg) {
  return (row * 4 + (seg ^ ((row >> 1) & 3))) * 8;  // short index of chunk start
}

// ---------------- K0: weight transpose + bf16 convert ----------------
// W1 (1024x512) -> W1t (512x1024) bf16 ; Wa1 (512x256) -> Wa1t (256x512) bf16
__global__ __launch_bounds__(256) void k0_prep(const float* __restrict__ W1,
                                               const float* __restrict__ Wa1,
                                               unsigned short* __restrict__ W1t,
                                               unsigned short* __restrict__ Wa1t) {
  int idx = blockIdx.x * 256 + threadIdx.x;
  if (idx < DIN * H) {                 // 524288
    int n = idx >> 10, k = idx & 1023; // W1t[n][k] = W1[k][n]
    W1t[idx] = f2bf(W1[k * H + n]);
  } else {
    int i2 = idx - DIN * H;            // < 131072
    int n = i2 >> 9, k = i2 & 511;     // Wa1t[n][k] = Wa1[k][n]
    Wa1t[i2] = f2bf(Wa1[k * HH + n]);
  }
}

// ---------------- K1: Eb = GELU(X @ W1 + b1), bf16 out ----------------
// M=65536, K=1024, N=512(full). BM=128, BN=512, BK=32. grid(512), 512 thr (8 waves 2x4).
// Full-N tile => X read exactly once from HBM; W1t (1MB) is L2-resident.
__global__ __launch_bounds__(512) void k1_gemm1(const float* __restrict__ X,
                                                const unsigned short* __restrict__ W1t,
                                                const float* __restrict__ b1,
                                                unsigned short* __restrict__ Eb) {
  __shared__ __align__(16) short lA[128 * 32];  // [row][k] bf16, swizzled chunks (8 KB)
  __shared__ __align__(16) short lB[512 * 32];  // [n][k]  bf16, swizzled chunks (32 KB)
  const int tid = threadIdx.x;
  const int rowBase = blockIdx.x * 128;
  const int lane = tid & 63;
  const int wave = tid >> 6;                // 0..7
  const int wr = wave >> 2, wc = wave & 3;  // 2x4 waves: each wave 64 rows x 128 cols
  const int l15 = lane & 15, quad = lane >> 4;

  floatx4 acc[4][8] = {};

  // A staging: thread owns chunk (row = tid>>2, seg = tid&3) = 8 floats -> 8 bf16 (16B)
  const int arow = tid >> 2, aseg = tid & 3;
  const float* aSrc = X + (size_t)(rowBase + arow) * DIN + aseg * 8;
  short* aDst = &lA[swz8(arow, aseg)];

  for (int kb = 0; kb < DIN; kb += 32) {
    __syncthreads();
    // --- stage B: 4 chunks/thread, async direct-to-LDS, pre-swizzled global source
#pragma unroll
    for (int s = 0; s < 4; s++) {
      int c = tid + s * 512;
      int n = c >> 2, slot = c & 3;
      int seg = slot ^ ((n >> 1) & 3);
      gl_lds16(W1t + (size_t)n * DIN + kb + seg * 8, &lB[c * 8]);
    }
    // --- stage A: fp32 -> bf16 via packed HW convert, swizzled ds_write
    {
      const floatx4* src = (const floatx4*)(aSrc + kb);
      floatx4 f0 = src[0], f1 = src[1];
      uintx4 u;
      u[0] = cvt_pk_bf16(f0[0], f0[1]);
      u[1] = cvt_pk_bf16(f0[2], f0[3]);
      u[2] = cvt_pk_bf16(f1[0], f1[1]);
      u[3] = cvt_pk_bf16(f1[2], f1[3]);
      *(uintx4*)aDst = u;
    }
    __syncthreads();
    // --- fragments (swizzled reads) + MFMA
    shortx8 aF[4], bF[8];
#pragma unroll
    for (int i = 0; i < 4; i++) {
      int r = wr * 64 + i * 16 + l15;
      aF[i] = *(const shortx8*)(&lA[swz8(r, quad)]);
    }
#pragma unroll
    for (int j = 0; j < 8; j++) {
      int r = wc * 128 + j * 16 + l15;
      bF[j] = *(const shortx8*)(&lB[swz8(r, quad)]);
    }
#pragma unroll
    for (int i = 0; i < 4; i++)
#pragma unroll
      for (int j = 0; j < 8; j++)
        acc[i][j] = __builtin_amdgcn_mfma_f32_16x16x32_bf16(aF[i], bF[j], acc[i][j], 0, 0, 0);
  }

  // --- epilogue: bias + exact GELU + bf16 store
  const int row0 = rowBase + wr * 64;
#pragma unroll
  for (int j = 0; j < 8; j++) {
    int col = wc * 128 + j * 16 + l15;
    float bias = b1[col];
#pragma unroll
    for (int i = 0; i < 4; i++) {
      int rb = row0 + i * 16 + quad * 4;
#pragma unroll
      for (int v = 0; v < 4; v++) {
        float x = acc[i][j][v] + bias;
        Eb[(size_t)(rb + v) * H + col] = f2bf_hw(gelu_exact(x));
      }
    }
  }
}

// ---------------- K2: scores += tanh(Eb @ Wa1 + ba1) . Wa2  (fused) ----------------
// M=65536, K=512, N=256. BM=BN=128. grid(2, 512), 256 thr. scores must be pre-zeroed.
__global__ __launch_bounds__(256) void k2_gemm2(const unsigned short* __restrict__ Eb,
                                                const unsigned short* __restrict__ Wa1t,
                                                const float* __restrict__ ba1,
                                                const float* __restrict__ Wa2,
                                                float* __restrict__ scores) {
  __shared__ __align__(16) short lA[128 * 32];
  __shared__ __align__(16) short lB[128 * 32];
  const int tid = threadIdx.x;
  const int colBase = blockIdx.x * 128;
  const int rowBase = blockIdx.y * 128;
  const int lane = tid & 63;
  const int wave = tid >> 6;
  const int wr = wave >> 1, wc = wave & 1;
  const int l15 = lane & 15, quad = lane >> 4;

  floatx4 acc[4][4] = {};

  for (int kb = 0; kb < H; kb += 32) {
    __syncthreads();
#pragma unroll
    for (int s = 0; s < 2; s++) {
      int c = tid + s * 256;
      int n = c >> 2, slot = c & 3;
      int seg = slot ^ ((n >> 1) & 3);
      gl_lds16(Eb + (size_t)(rowBase + n) * H + kb + seg * 8, &lA[c * 8]);
      gl_lds16(Wa1t + (size_t)(colBase + n) * H + kb + seg * 8, &lB[c * 8]);
    }
    __syncthreads();
    shortx8 aF[4], bF[4];
#pragma unroll
    for (int i = 0; i < 4; i++) {
      int r = wr * 64 + i * 16 + l15;
      aF[i] = *(const shortx8*)(&lA[swz8(r, quad)]);
    }
#pragma unroll
    for (int j = 0; j < 4; j++) {
      int r = wc * 64 + j * 16 + l15;
      bF[j] = *(const shortx8*)(&lB[swz8(r, quad)]);
    }
#pragma unroll
    for (int i = 0; i < 4; i++)
#pragma unroll
      for (int j = 0; j < 4; j++)
        acc[i][j] = __builtin_amdgcn_mfma_f32_16x16x32_bf16(aF[i], bF[j], acc[i][j], 0, 0, 0);
  }

  // epilogue: p[i][v] = sum_cols tanh(acc + ba1[col]) * Wa2[col]; reduce over 16 lanes
  float p[4][4];
#pragma unroll
  for (int i = 0; i < 4; i++)
#pragma unroll
    for (int v = 0; v < 4; v++) p[i][v] = 0.0f;
#pragma unroll
  for (int j = 0; j < 4; j++) {
    int col = colBase + wc * 64 + j * 16 + l15;
    float bias = ba1[col];
    float wa2 = Wa2[col];
#pragma unroll
    for (int i = 0; i < 4; i++)
#pragma unroll
      for (int v = 0; v < 4; v++)
        p[i][v] += fast_tanh(acc[i][j][v] + bias) * wa2;
  }
#pragma unroll
  for (int i = 0; i < 4; i++)
#pragma unroll
    for (int v = 0; v < 4; v++) {
      float t = p[i][v];
      t += __shfl_xor(t, 1, 16);
      t += __shfl_xor(t, 2, 16);
      t += __shfl_xor(t, 4, 16);
      t += __shfl_xor(t, 8, 16);
      p[i][v] = t;
    }
  if (l15 == 0) {
    int row0 = rowBase + wr * 64 + quad * 4;
#pragma unroll
    for (int i = 0; i < 4; i++)
#pragma unroll
      for (int v = 0; v < 4; v++)
        atomicAdd(&scores[row0 + i * 16 + v], p[i][v]);
  }
}

// ---------------- K3a: per-region softmax weights ----------------
__global__ __launch_bounds__(256) void k3a_softmax(const float* __restrict__ scores,
                                                   float* __restrict__ wts) {
  const int r = blockIdx.x, tid = threadIdx.x;
  __shared__ float red[256];
  float m = -1e30f;
  for (int j = tid; j < MPR; j += 256) m = fmaxf(m, scores[r + NREG * j]);
  red[tid] = m;
  __syncthreads();
  for (int s = 128; s > 0; s >>= 1) {
    if (tid < s) red[tid] = fmaxf(red[tid], red[tid + s]);
    __syncthreads();
  }
  float mx = red[0];
  __syncthreads();
  float sum = 0.0f;
  for (int j = tid; j < MPR; j += 256) sum += expf(scores[r + NREG * j] - mx);
  red[tid] = sum;
  __syncthreads();
  for (int s = 128; s > 0; s >>= 1) {
    if (tid < s) red[tid] += red[tid + s];
    __syncthreads();
  }
  float inv = 1.0f / red[0];
  for (int j = tid; j < MPR; j += 256)
    wts[r + NREG * j] = expf(scores[r + NREG * j] - mx) * inv;
}

// ---------------- K3b: region_features[r][h] = sum_m w * Eb ----------------
// grid(32 mchunks, 16 regions), 256 thr (each thread 2 h via dword load). rf pre-zeroed.
__global__ __launch_bounds__(256) void k3b_wsum(const unsigned short* __restrict__ Eb,
                                                const float* __restrict__ wts,
                                                float* __restrict__ rf) {
  const int r = blockIdx.y;
  const int mc = blockIdx.x;
  const int tid = threadIdx.x;
  float a0 = 0.0f, a1 = 0.0f;
  for (int j = mc * 128; j < mc * 128 + 128; j++) {
    int n = r + NREG * j;
    float w = wts[n];
    unsigned v = *(const unsigned*)(Eb + (size_t)n * H + tid * 2);
    a0 += w * bf2f((unsigned short)(v & 0xffffu));
    a1 += w * bf2f((unsigned short)(v >> 16));
  }
  atomicAdd(&rf[r * H + tid * 2], a0);
  atomicAdd(&rf[r * H + tid * 2 + 1], a1);
}

// ---------------- K4a: slide_emb = GELU(rf @ Ws + bs) ----------------
__global__ __launch_bounds__(256) void k4a_slide(const float* __restrict__ rf,
                                                 const float* __restrict__ Ws,
                                                 const float* __restrict__ bs,
                                                 float* __restrict__ se) {
  const int r = blockIdx.x, tid = threadIdx.x;
  __shared__ float lrf[H];
  lrf[tid] = rf[r * H + tid];
  lrf[tid + 256] = rf[r * H + tid + 256];
  __syncthreads();
  float a0 = 0.0f, a1 = 0.0f;
  for (int k = 0; k < H; k++) {
    float x = lrf[k];
    a0 += x * Ws[k * H + tid];
    a1 += x * Ws[k * H + tid + 256];
  }
  se[r * H + tid] = gelu_exact(a0 + bs[tid]);
  se[r * H + tid + 256] = gelu_exact(a1 + bs[tid + 256]);
}

// ---------------- K4b: sscore[r] = tanh(se @ Wsa1 + bsa1) . Wsa2 + bsa2 ----------------
__global__ __launch_bounds__(256) void k4b_sscore(const float* __restrict__ se,
                                                  const float* __restrict__ Wsa1,
                                                  const float* __restrict__ bsa1,
                                                  const float* __restrict__ Wsa2,
                                                  const float* __restrict__ bsa2,
                                                  float* __restrict__ ss) {
  const int r = blockIdx.x, tid = threadIdx.x;
  __shared__ float lse[H];
  __shared__ float red[256];
  lse[tid] = se[r * H + tid];
  lse[tid + 256] = se[r * H + tid + 256];
  __syncthreads();
  float a = 0.0f;
  for (int k = 0; k < H; k++) a += lse[k] * Wsa1[k * HH + tid];
  red[tid] = tanhf(a + bsa1[tid]) * Wsa2[tid];
  __syncthreads();
  for (int s = 128; s > 0; s >>= 1) {
    if (tid < s) red[tid] += red[tid + s];
    __syncthreads();
  }
  if (tid == 0) ss[r] = red[0] + bsa2[0];
}

// ---------------- K4c: softmax over regions + classifier ----------------
__global__ __launch_bounds__(256) void k4c_final(const float* __restrict__ se,
                                                 const float* __restrict__ ss,
                                                 const float* __restrict__ Wc1,
                                                 const float* __restrict__ bc1,
                                                 const float* __restrict__ Wc2,
                                                 const float* __restrict__ bc2,
                                                 float* __restrict__ out) {
  const int tid = threadIdx.x;
  __shared__ float srep[H];
  __shared__ float r0[256], r1[256];
  // softmax over 16 region scores (computed redundantly per thread)
  float mx = -1e30f;
  for (int i = 0; i < NREG; i++) mx = fmaxf(mx, ss[i]);
  float wv[NREG];
  float den = 0.0f;
  for (int i = 0; i < NREG; i++) { wv[i] = expf(ss[i] - mx); den += wv[i]; }
  float inv = 1.0f / den;
  float s0 = 0.0f, s1 = 0.0f;
  for (int i = 0; i < NREG; i++) {
    float w = wv[i] * inv;
    s0 += w * se[i * H + tid];
    s1 += w * se[i * H + tid + 256];
  }
  srep[tid] = s0;
  srep[tid + 256] = s1;
  __syncthreads();
  float a = 0.0f;
  for (int k = 0; k < H; k++) a += srep[k] * Wc1[k * HH + tid];
  float g = gelu_exact(a + bc1[tid]);
  r0[tid] = g * Wc2[tid * 2];
  r1[tid] = g * Wc2[tid * 2 + 1];
  __syncthreads();
  for (int s = 128; s > 0; s >>= 1) {
    if (tid < s) { r0[tid] += r0[tid + s]; r1[tid] += r1[tid + s]; }
    __syncthreads();
  }
  if (tid == 0) {
    out[0] = r0[0] + bc2[0];
    out[1] = r1[0] + bc2[1];
  }
}

// ---------------- launcher ----------------
extern "C" void kernel_launch(void* const* d_in, const int* in_sizes, int n_in,
                              void* d_out, int out_size, void* d_ws, size_t ws_size,
                              hipStream_t stream) {
  const float* X    = (const float*)d_in[0];
  const float* W1   = (const float*)d_in[1];
  const float* b1   = (const float*)d_in[2];
  const float* Wa1  = (const float*)d_in[3];
  const float* ba1  = (const float*)d_in[4];
  const float* Wa2  = (const float*)d_in[5];
  // d_in[6] = ba2: constant shift inside softmax -> no effect, unused
  const float* Ws   = (const float*)d_in[7];
  const float* bs   = (const float*)d_in[8];
  const float* Wsa1 = (const float*)d_in[9];
  const float* bsa1 = (const float*)d_in[10];
  const float* Wsa2 = (const float*)d_in[11];
  const float* bsa2 = (const float*)d_in[12];
  const float* Wc1  = (const float*)d_in[13];
  const float* bc1  = (const float*)d_in[14];
  const float* Wc2  = (const float*)d_in[15];
  const float* bc2  = (const float*)d_in[16];
  float* out = (float*)d_out;

  char* ws = (char*)d_ws;
  // workspace layout (all 16B-aligned)
  constexpr size_t OFF_W1T  = 0;                         // 512*1024*2 = 1 MiB
  constexpr size_t OFF_WA1T = OFF_W1T + (size_t)H * DIN * 2;        // +256 KiB
  constexpr size_t OFF_EB   = OFF_WA1T + (size_t)HH * H * 2;        // +64 MiB
  constexpr size_t OFF_SC   = OFF_EB + (size_t)NTOK * H * 2;        // scores 256 KiB
  constexpr size_t OFF_RF   = OFF_SC + (size_t)NTOK * 4;            // rf 32 KiB (zeroed with scores)
  constexpr size_t OFF_WT   = OFF_RF + (size_t)NREG * H * 4;        // wts 256 KiB
  constexpr size_t OFF_SE   = OFF_WT + (size_t)NTOK * 4;            // se 32 KiB
  constexpr size_t OFF_SS   = OFF_SE + (size_t)NREG * H * 4;        // ss 64 B

  unsigned short* W1t  = (unsigned short*)(ws + OFF_W1T);
  unsigned short* Wa1t = (unsigned short*)(ws + OFF_WA1T);
  unsigned short* Eb   = (unsigned short*)(ws + OFF_EB);
  float* scores = (float*)(ws + OFF_SC);
  float* rf     = (float*)(ws + OFF_RF);
  float* wts    = (float*)(ws + OFF_WT);
  float* se     = (float*)(ws + OFF_SE);
  float* ssb    = (float*)(ws + OFF_SS);

  // zero the atomic accumulators (scores + rf are contiguous)
  hipMemsetAsync(scores, 0, (size_t)NTOK * 4 + (size_t)NREG * H * 4, stream);

  k0_prep<<<(DIN * H + HH * H) / 256, 256, 0, stream>>>(W1, Wa1, W1t, Wa1t);
  k1_gemm1<<<512, 512, 0, stream>>>(X, W1t, b1, Eb);
  k2_gemm2<<<dim3(2, 512), 256, 0, stream>>>(Eb, Wa1t, ba1, Wa2, scores);
  k3a_softmax<<<NREG, 256, 0, stream>>>(scores, wts);
  k3b_wsum<<<dim3(32, NREG), 256, 0, stream>>>(Eb, wts, rf);
  k4a_slide<<<NREG, 256, 0, stream>>>(rf, Ws, bs, se);
  k4b_sscore<<<NREG, 256, 0, stream>>>(se, Wsa1, bsa1, Wsa2, bsa2, ssb);
  k4c_final<<<1, 256, 0, stream>>>(se, ssb, Wc1, bc1, Wc2, bc2, out);
}